// Round 1
// baseline (203.295 us; speedup 1.0000x reference)
//
#include <hip/hip_runtime.h>
#include <math.h>

#define HH 192
#define WW 320
#define CC 3
#define DTOT 507.0f
#define XS 64      // w-span per block
#define TV 64      // v-chunk
#define KD 39      // 3 channels * 13 dy
#define TX 76      // XS + 12 halo
#define TU 76      // TV + 12 halo
#define TUP 81     // padded LDS column stride for T (odd -> conflict-free diag reads)
#define NSPAN 5    // WW / XS
#define NCHUNK 5   // WW / TV

// ---------- kernel 0: scale = fx * || (r_extri @ inv(l_extri))[:3,3] || ----------
__global__ void prep_kernel(const float* __restrict__ li, const float* __restrict__ le,
                            const float* __restrict__ re, float* __restrict__ ws) {
    if (threadIdx.x != 0 || blockIdx.x != 0) return;
    float a[4][4], inv[4][4];
    for (int i = 0; i < 4; ++i)
        for (int j = 0; j < 4; ++j) { a[i][j] = le[i*4+j]; inv[i][j] = (i == j) ? 1.0f : 0.0f; }
    // Gauss-Jordan with partial pivoting
    for (int c = 0; c < 4; ++c) {
        int p = c; float mx = fabsf(a[c][c]);
        for (int r = c+1; r < 4; ++r) { float v = fabsf(a[r][c]); if (v > mx) { mx = v; p = r; } }
        if (p != c) for (int j = 0; j < 4; ++j) {
            float t = a[c][j]; a[c][j] = a[p][j]; a[p][j] = t;
            t = inv[c][j]; inv[c][j] = inv[p][j]; inv[p][j] = t;
        }
        float id = 1.0f / a[c][c];
        for (int j = 0; j < 4; ++j) { a[c][j] *= id; inv[c][j] *= id; }
        for (int r = 0; r < 4; ++r) if (r != c) {
            float f = a[r][c];
            for (int j = 0; j < 4; ++j) { a[r][j] -= f*a[c][j]; inv[r][j] -= f*inv[c][j]; }
        }
    }
    float rel[3];
    for (int i = 0; i < 3; ++i)
        rel[i] = re[i*4+0]*inv[0][3] + re[i*4+1]*inv[1][3] + re[i*4+2]*inv[2][3] + re[i*4+3]*inv[3][3];
    float baseline = sqrtf(rel[0]*rel[0] + rel[1]*rel[1] + rel[2]*rel[2]);
    ws[0] = li[0] * baseline;   // fx = l_intri[0,0]
}

// ---------- kernel 1: per-pixel patch mean / inv-norm via 13x13x3 window ----------
__global__ void stats_kernel(const float* __restrict__ limg, const float* __restrict__ rimg,
                             float* __restrict__ mul_, float* __restrict__ mur_,
                             float* __restrict__ invr_) {
    int idx = blockIdx.x * blockDim.x + threadIdx.x;
    if (idx >= 2 * HH * WW) return;
    int side = idx / (HH * WW);
    int p = idx % (HH * WW);
    int h = p / WW, w = p % WW;
    const float* img = side ? rimg : limg;
    float s1 = 0.0f, s2 = 0.0f;
    for (int c = 0; c < CC; ++c) {
        for (int dy = -6; dy <= 6; ++dy) {
            int y = h + dy;
            if (y < 0 || y >= HH) continue;
            const float* row = img + (c*HH + y)*WW;
            for (int dx = -6; dx <= 6; ++dx) {
                int x = w + dx;
                if (x < 0 || x >= WW) continue;
                float v = row[x];
                s1 += v;
                s2 = fmaf(v, v, s2);
            }
        }
    }
    float mu = s1 / DTOT;
    if (side == 0) {
        mul_[p] = mu;
    } else {
        float var = fmaxf(s2 - s1*s1/DTOT, 0.0f);
        float n = sqrtf(var);
        mur_[p] = mu;
        invr_[p] = 1.0f / (n + 1e-5f);
    }
}

// ---------- kernel 2: per-row K=39 GEMM -> diagonal 13-box -> argmax -> depth ----------
__global__ __launch_bounds__(256) void match_kernel(
        const float* __restrict__ limg, const float* __restrict__ rimg,
        const float* __restrict__ mul_, const float* __restrict__ mur_,
        const float* __restrict__ invr_, const float* __restrict__ ws,
        float* __restrict__ out) {
    __shared__ float Ls[KD][TX];       // left slab: 39 x 76
    __shared__ float Rs[KD][TU];       // right slab chunk: 39 x 76
    __shared__ float Tt[TX][TUP];      // column-dot tile, padded stride 81
    __shared__ float redS[4][XS];
    __shared__ int   redV[4][XS];

    const int span = blockIdx.x;       // 0..4
    const int h    = blockIdx.y;       // 0..191
    const int wlo  = span * XS;
    const int tid  = threadIdx.x;
    const int lane = tid & 63;
    const int wave = tid >> 6;

    // stage left slab (zero-padded)
    for (int i = tid; i < KD*TX; i += 256) {
        int k = i / TX, xl = i % TX;
        int c = k / 13, dy = k % 13;
        int y = h - 6 + dy, x = wlo - 6 + xl;
        float v = 0.0f;
        if (y >= 0 && y < HH && x >= 0 && x < WW) v = limg[(c*HH + y)*WW + x];
        Ls[k][xl] = v;
    }

    float best = -1e30f;
    int bestv = 0;
    const float muL = mul_[h*WW + wlo + lane];   // this lane's w

    for (int ch = 0; ch < NCHUNK; ++ch) {        // v-chunks ascending (tie-break order)
        const int ulo = ch * TV;
        // stage right slab chunk (zero-padded)
        for (int i = tid; i < KD*TU; i += 256) {
            int k = i / TU, uc = i % TU;
            int c = k / 13, dy = k % 13;
            int y = h - 6 + dy, u = ulo - 6 + uc;
            float v = 0.0f;
            if (y >= 0 && y < HH && u >= 0 && u < WW) v = rimg[(c*HH + y)*WW + u];
            Rs[k][uc] = v;
        }
        __syncthreads();   // Rs ready; also orders prev Phase-B T-reads before T-writes

        // Phase A: T[i][j] = sum_k Ls[k][i]*Rs[k][j]; 19x19 tiles of 4x4
        for (int t = tid; t < 361; t += 256) {
            int ti = t % 19, tj = t / 19;
            int i0 = ti * 4, j0 = tj * 4;
            float a00=0,a01=0,a02=0,a03=0, a10=0,a11=0,a12=0,a13=0;
            float a20=0,a21=0,a22=0,a23=0, a30=0,a31=0,a32=0,a33=0;
            for (int k = 0; k < KD; ++k) {
                float4 la = *(const float4*)&Ls[k][i0];
                float4 rb = *(const float4*)&Rs[k][j0];
                a00 = fmaf(la.x, rb.x, a00); a01 = fmaf(la.x, rb.y, a01);
                a02 = fmaf(la.x, rb.z, a02); a03 = fmaf(la.x, rb.w, a03);
                a10 = fmaf(la.y, rb.x, a10); a11 = fmaf(la.y, rb.y, a11);
                a12 = fmaf(la.y, rb.z, a12); a13 = fmaf(la.y, rb.w, a13);
                a20 = fmaf(la.z, rb.x, a20); a21 = fmaf(la.z, rb.y, a21);
                a22 = fmaf(la.z, rb.z, a22); a23 = fmaf(la.z, rb.w, a23);
                a30 = fmaf(la.w, rb.x, a30); a31 = fmaf(la.w, rb.y, a31);
                a32 = fmaf(la.w, rb.z, a32); a33 = fmaf(la.w, rb.w, a33);
            }
            float* tr0 = &Tt[i0+0][j0]; tr0[0]=a00; tr0[1]=a01; tr0[2]=a02; tr0[3]=a03;
            float* tr1 = &Tt[i0+1][j0]; tr1[0]=a10; tr1[1]=a11; tr1[2]=a12; tr1[3]=a13;
            float* tr2 = &Tt[i0+2][j0]; tr2[0]=a20; tr2[1]=a21; tr2[2]=a22; tr2[3]=a23;
            float* tr3 = &Tt[i0+3][j0]; tr3[0]=a30; tr3[1]=a31; tr3[2]=a32; tr3[3]=a33;
        }
        __syncthreads();   // T ready

        // Phase B: diagonal 13-box sums; lane = w, wave covers 16 v's of the chunk
        for (int vi = 0; vi < 16; ++vi) {
            int vc = wave * 16 + vi;       // v - ulo
            int v  = ulo + vc;
            const float* tp = &Tt[lane][vc];
            float S = 0.0f;
            #pragma unroll
            for (int dxp = 0; dxp < 13; ++dxp)
                S += tp[dxp * (TUP + 1)];  // (lane+dxp)*81 + (vc+dxp)
            float muR = mur_[h*WW + v];
            float ivR = invr_[h*WW + v];
            float score = (S - DTOT * muL * muR) * ivR;
            if (score > best) { best = score; bestv = v; }
        }
        // no barrier needed here: next Rs-stage touches only Rs, and the sync
        // after that stage orders this Phase B's T-reads before next T-writes.
    }

    // merge the 4 waves' candidates per w (tie -> lower v, matching jnp.argmax)
    redS[wave][lane] = best;
    redV[wave][lane] = bestv;
    __syncthreads();
    if (tid < XS) {
        float b = redS[0][tid]; int bv = redV[0][tid];
        for (int wv = 1; wv < 4; ++wv) {
            float s = redS[wv][tid]; int v2 = redV[wv][tid];
            if (s > b || (s == b && v2 < bv)) { b = s; bv = v2; }
        }
        int w = wlo + tid;
        float disp = fabsf((float)bv - (float)w);
        disp = fmaxf(disp, 0.001f);
        out[h*WW + w] = ws[0] / disp;
    }
}

extern "C" void kernel_launch(void* const* d_in, const int* in_sizes, int n_in,
                              void* d_out, int out_size, void* d_ws, size_t ws_size,
                              hipStream_t stream) {
    const float* limg   = (const float*)d_in[0];
    const float* rimg   = (const float*)d_in[1];
    const float* lintri = (const float*)d_in[2];
    const float* lex    = (const float*)d_in[4];
    const float* rex    = (const float*)d_in[5];
    float* out = (float*)d_out;
    float* ws  = (float*)d_ws;
    float* mul_  = ws + 64;
    float* mur_  = mul_ + HH*WW;
    float* invr_ = mur_ + HH*WW;

    hipLaunchKernelGGL(prep_kernel, dim3(1), dim3(64), 0, stream, lintri, lex, rex, ws);
    int nstat = 2 * HH * WW;
    hipLaunchKernelGGL(stats_kernel, dim3((nstat + 255)/256), dim3(256), 0, stream,
                       limg, rimg, mul_, mur_, invr_);
    hipLaunchKernelGGL(match_kernel, dim3(NSPAN, HH), dim3(256), 0, stream,
                       limg, rimg, mul_, mur_, invr_, ws, out);
}

// Round 2
// 168.483 us; speedup vs baseline: 1.2066x; 1.2066x over previous
//
#include <hip/hip_runtime.h>
#include <math.h>

#define HH 192
#define WW 320
#define CC 3
#define DTOT 507.0f
#define XS 64      // w-span per block
#define TV 64      // v-chunk
#define KD 39      // 3 channels * 13 dy
#define TX 76      // XS + 12 halo
#define TU 76      // TV + 12 halo
#define TUP 81     // padded LDS column stride for T (odd -> conflict-free diag reads)
#define NSPAN 5    // WW / XS
#define NCHUNK 5   // WW / TV

// ---------- kernel 0: scale = fx * || (r_extri @ inv(l_extri))[:3,3] || ----------
__global__ void prep_kernel(const float* __restrict__ li, const float* __restrict__ le,
                            const float* __restrict__ re, float* __restrict__ ws) {
    if (threadIdx.x != 0 || blockIdx.x != 0) return;
    float a[4][4], inv[4][4];
    for (int i = 0; i < 4; ++i)
        for (int j = 0; j < 4; ++j) { a[i][j] = le[i*4+j]; inv[i][j] = (i == j) ? 1.0f : 0.0f; }
    // Gauss-Jordan with partial pivoting
    for (int c = 0; c < 4; ++c) {
        int p = c; float mx = fabsf(a[c][c]);
        for (int r = c+1; r < 4; ++r) { float v = fabsf(a[r][c]); if (v > mx) { mx = v; p = r; } }
        if (p != c) for (int j = 0; j < 4; ++j) {
            float t = a[c][j]; a[c][j] = a[p][j]; a[p][j] = t;
            t = inv[c][j]; inv[c][j] = inv[p][j]; inv[p][j] = t;
        }
        float id = 1.0f / a[c][c];
        for (int j = 0; j < 4; ++j) { a[c][j] *= id; inv[c][j] *= id; }
        for (int r = 0; r < 4; ++r) if (r != c) {
            float f = a[r][c];
            for (int j = 0; j < 4; ++j) { a[r][j] -= f*a[c][j]; inv[r][j] -= f*inv[c][j]; }
        }
    }
    float rel[3];
    for (int i = 0; i < 3; ++i)
        rel[i] = re[i*4+0]*inv[0][3] + re[i*4+1]*inv[1][3] + re[i*4+2]*inv[2][3] + re[i*4+3]*inv[3][3];
    float baseline = sqrtf(rel[0]*rel[0] + rel[1]*rel[1] + rel[2]*rel[2]);
    ws[0] = li[0] * baseline;   // fx = l_intri[0,0]
}

// ---------- kernel 1: per-row K=39 GEMM -> diagonal 13-box -> argmax -> depth ----------
// Stats (patch mean / inv-norm) are computed in-block from the staged slabs via
// column sums: colL[x] = sum_k Ls[k][x]; patch sum = 13-tap over columns. This is
// the same zero-padded 507-element window sum as the reference, reordered.
__global__ __launch_bounds__(256) void match_kernel(
        const float* __restrict__ limg, const float* __restrict__ rimg,
        const float* __restrict__ ws, float* __restrict__ out) {
    __shared__ float Ls[KD][TX];       // left slab: 39 x 76
    __shared__ float Rs[KD][TU];       // right slab chunk: 39 x 76
    __shared__ float Tt[TX][TUP];      // column-dot tile, padded stride 81
    __shared__ float colL[TX];         // per-column sums of Ls
    __shared__ float colR1[TU];        // per-column sums of Rs
    __shared__ float colR2[TU];        // per-column sums of Rs^2
    __shared__ float smuR[TV];         // mu_R per v in chunk
    __shared__ float sivR[TV];         // 1/(norm_R+eps) per v in chunk
    __shared__ float redS[4][XS];
    __shared__ int   redV[4][XS];

    const int span = blockIdx.x;       // 0..4
    const int h    = blockIdx.y;       // 0..191
    const int wlo  = span * XS;
    const int tid  = threadIdx.x;
    const int lane = tid & 63;
    const int wave = tid >> 6;

    // stage left slab (zero-padded)
    for (int i = tid; i < KD*TX; i += 256) {
        int k = i / TX, xl = i % TX;
        int c = k / 13, dy = k % 13;
        int y = h - 6 + dy, x = wlo - 6 + xl;
        float v = 0.0f;
        if (y >= 0 && y < HH && x >= 0 && x < WW) v = limg[(c*HH + y)*WW + x];
        Ls[k][xl] = v;
    }
    __syncthreads();                   // B0: Ls ready

    if (tid < TX) {
        float s = 0.0f;
        for (int k = 0; k < KD; ++k) s += Ls[k][tid];
        colL[tid] = s;
    }
    __syncthreads();                   // B0b: colL ready

    // this lane's w = wlo + lane; patch columns = slab x in [lane, lane+12]
    float muL;
    {
        float s = 0.0f;
        #pragma unroll
        for (int dx = 0; dx < 13; ++dx) s += colL[lane + dx];
        muL = s / DTOT;
    }

    float best = -1e30f;
    int bestv = 0;

    for (int ch = 0; ch < NCHUNK; ++ch) {        // v-chunks ascending (tie-break order)
        const int ulo = ch * TV;
        // stage right slab chunk (zero-padded)
        for (int i = tid; i < KD*TU; i += 256) {
            int k = i / TU, uc = i % TU;
            int c = k / 13, dy = k % 13;
            int y = h - 6 + dy, u = ulo - 6 + uc;
            float v = 0.0f;
            if (y >= 0 && y < HH && u >= 0 && u < WW) v = rimg[(c*HH + y)*WW + u];
            Rs[k][uc] = v;
        }
        __syncthreads();   // B1: Rs ready; also orders prev Phase-B T-reads before T-writes

        // column sums of R slab (and squares)
        if (tid < TU) {
            float s1 = 0.0f, s2 = 0.0f;
            for (int k = 0; k < KD; ++k) {
                float v = Rs[k][tid];
                s1 += v;
                s2 = fmaf(v, v, s2);
            }
            colR1[tid] = s1;
            colR2[tid] = s2;
        }

        // Phase A: T[i][j] = sum_k Ls[k][i]*Rs[k][j]; 19x19 tiles of 4x4
        for (int t = tid; t < 361; t += 256) {
            int ti = t % 19, tj = t / 19;
            int i0 = ti * 4, j0 = tj * 4;
            float a00=0,a01=0,a02=0,a03=0, a10=0,a11=0,a12=0,a13=0;
            float a20=0,a21=0,a22=0,a23=0, a30=0,a31=0,a32=0,a33=0;
            for (int k = 0; k < KD; ++k) {
                float4 la = *(const float4*)&Ls[k][i0];
                float4 rb = *(const float4*)&Rs[k][j0];
                a00 = fmaf(la.x, rb.x, a00); a01 = fmaf(la.x, rb.y, a01);
                a02 = fmaf(la.x, rb.z, a02); a03 = fmaf(la.x, rb.w, a03);
                a10 = fmaf(la.y, rb.x, a10); a11 = fmaf(la.y, rb.y, a11);
                a12 = fmaf(la.y, rb.z, a12); a13 = fmaf(la.y, rb.w, a13);
                a20 = fmaf(la.z, rb.x, a20); a21 = fmaf(la.z, rb.y, a21);
                a22 = fmaf(la.z, rb.z, a22); a23 = fmaf(la.z, rb.w, a23);
                a30 = fmaf(la.w, rb.x, a30); a31 = fmaf(la.w, rb.y, a31);
                a32 = fmaf(la.w, rb.z, a32); a33 = fmaf(la.w, rb.w, a33);
            }
            float* tr0 = &Tt[i0+0][j0]; tr0[0]=a00; tr0[1]=a01; tr0[2]=a02; tr0[3]=a03;
            float* tr1 = &Tt[i0+1][j0]; tr1[0]=a10; tr1[1]=a11; tr1[2]=a12; tr1[3]=a13;
            float* tr2 = &Tt[i0+2][j0]; tr2[0]=a20; tr2[1]=a21; tr2[2]=a22; tr2[3]=a23;
            float* tr3 = &Tt[i0+3][j0]; tr3[0]=a30; tr3[1]=a31; tr3[2]=a32; tr3[3]=a33;
        }
        __syncthreads();   // B2: T ready, colR ready

        // per-v stats for this chunk (v = ulo + t, slab cols t..t+12)
        if (tid < TV) {
            float s1 = 0.0f, s2 = 0.0f;
            #pragma unroll
            for (int dx = 0; dx < 13; ++dx) { s1 += colR1[tid + dx]; s2 += colR2[tid + dx]; }
            float mu = s1 / DTOT;
            float var = fmaxf(s2 - s1*s1/DTOT, 0.0f);
            smuR[tid] = mu;
            sivR[tid] = 1.0f / (sqrtf(var) + 1e-5f);
        }
        __syncthreads();   // B3: smuR/sivR ready

        // Phase B: diagonal 13-box sums; lane = w, wave covers 16 v's of the chunk
        for (int vi = 0; vi < 16; ++vi) {
            int vc = wave * 16 + vi;       // v - ulo
            int v  = ulo + vc;
            const float* tp = &Tt[lane][vc];
            float S = 0.0f;
            #pragma unroll
            for (int dxp = 0; dxp < 13; ++dxp)
                S += tp[dxp * (TUP + 1)];  // (lane+dxp)*81 + (vc+dxp)
            float score = (S - DTOT * muL * smuR[vc]) * sivR[vc];
            if (score > best) { best = score; bestv = v; }
        }
        // next Rs/colR staging writes are ordered after these T/smuR reads by B1/B2.
    }

    // merge the 4 waves' candidates per w (tie -> lower v, matching jnp.argmax)
    redS[wave][lane] = best;
    redV[wave][lane] = bestv;
    __syncthreads();
    if (tid < XS) {
        float b = redS[0][tid]; int bv = redV[0][tid];
        for (int wv = 1; wv < 4; ++wv) {
            float s = redS[wv][tid]; int v2 = redV[wv][tid];
            if (s > b || (s == b && v2 < bv)) { b = s; bv = v2; }
        }
        int w = wlo + tid;
        float disp = fabsf((float)bv - (float)w);
        disp = fmaxf(disp, 0.001f);
        out[h*WW + w] = ws[0] / disp;
    }
}

extern "C" void kernel_launch(void* const* d_in, const int* in_sizes, int n_in,
                              void* d_out, int out_size, void* d_ws, size_t ws_size,
                              hipStream_t stream) {
    const float* limg   = (const float*)d_in[0];
    const float* rimg   = (const float*)d_in[1];
    const float* lintri = (const float*)d_in[2];
    const float* lex    = (const float*)d_in[4];
    const float* rex    = (const float*)d_in[5];
    float* out = (float*)d_out;
    float* ws  = (float*)d_ws;

    hipLaunchKernelGGL(prep_kernel, dim3(1), dim3(64), 0, stream, lintri, lex, rex, ws);
    hipLaunchKernelGGL(match_kernel, dim3(NSPAN, HH), dim3(256), 0, stream,
                       limg, rimg, ws, out);
}